// Round 14
// baseline (115.142 us; speedup 1.0000x reference)
//
#include <hip/hip_runtime.h>

#define NDIM 128
#define NOBS 16
#define LOG2E 1.44269504088896341f

typedef float f32x2 __attribute__((ext_vector_type(2)));

__device__ __forceinline__ float frcp(float x) { return __builtin_amdgcn_rcpf(x); }
__device__ __forceinline__ float fexp2(float x) { return __builtin_amdgcn_exp2f(x); }
__device__ __forceinline__ float fexp(float x) { return __builtin_amdgcn_exp2f(x * LOG2E); }
__device__ __forceinline__ float sigf(float v) { return frcp(1.0f + fexp(-v)); }
__device__ __forceinline__ float siluf(float v) { return v * sigf(v); }
__device__ __forceinline__ float dsiluf(float v) {
    float s = sigf(v);
    return s * (1.0f + v * (1.0f - s));
}
__device__ __forceinline__ f32x2 pkfma(f32x2 a, f32x2 b, f32x2 c) {
    return __builtin_elementwise_fma(a, b, c);
}

// ---- LDS layouts: both phases union into one 60.6 KB block ----------------
// Both structs BEGIN with the identical 512-byte x image, so x loaded in the
// H phase persists into the JR phase (no H-phase field aliases offset 0-511).
struct HS {
    float  sx[8][NOBS];
    float  sh[8][NDIM];
    float4 sKVQ[8][NDIM];   // {K, V, 1.0, K*V}
    float  sz[8][NDIM];
    float4 sC[8][NDIM];     // {wt, wt*Q, wt*Q*t, Qe}
    float4 sD[8][NDIM];     // {dQp, dKp, dVp, 0}
    float  sy[8][26], swp[8][26], sdwp[8][26];
    float  skmax[4][4], skmin[4][4];
    float  sred[4][4][2];
};
struct JRS {
    float sx[128];          // aliases HS::sx — same linear layout
    float sh[2][NDIM][8];
    float sK[2][NDIM][8];
    float sV[2][NDIM][8];
    float sz[2][8][132];
    float sw[2][NDIM];
    float skr[2][2][2][8];
};
union SU { HS h; JRS jr; };

// ---------------------------------------------------------------------------
// Phase 1: H-module gradient for one batch (8 rows). Round-11 configuration
// (unrolls B/C/F: 4, G: 8) + s_setprio(1) around the exp-dense stages C, F.
// ---------------------------------------------------------------------------
__device__ __forceinline__ void h_path(
    int b, int tid, HS& S,
    const float* __restrict__ x,
    const float* __restrict__ Win, const float* __restrict__ bin,
    const float* __restrict__ Aq, const float* __restrict__ Ak, const float* __restrict__ Av,
    const float* __restrict__ Bq, const float* __restrict__ Bk, const float* __restrict__ Bv,
    const float* __restrict__ Wout, const float* __restrict__ bout,
    float* sdHf)
{
    const int tl = tid & 127, tg = tid >> 7, wid = tid >> 6, r0 = tg * 4;

    if (tid < 128) S.sx[tid >> 4][tid & 15] = x[b * 128 + tid];
    __syncthreads();

    // ---- A: h = silu(x @ Win + bin) ----
    float hp[4];
    {
        float acc[4];
        const float b0 = bin[tl];
        #pragma unroll
        for (int r = 0; r < 4; ++r) acc[r] = b0;
        #pragma unroll
        for (int o = 0; o < NOBS; ++o) {
            const float w = Win[o * NDIM + tl];
            #pragma unroll
            for (int r = 0; r < 4; ++r) acc[r] = fmaf(w, S.sx[r0 + r][o], acc[r]);
        }
        #pragma unroll
        for (int r = 0; r < 4; ++r) { hp[r] = acc[r]; S.sh[r0 + r][tl] = siluf(acc[r]); }
    }
    __syncthreads();

    // ---- B: Q,K,V = silu(A h + B); packed pairs; unroll 4 ----
    float Qp[4], Kp[4], Vp[4], Qv[4], Kv[4], Vv[4], Qe[4];
    {
        f32x2 aq2[4], ak2[4], av2[4];
        const float bq = Bq[tl], bk = Bk[tl], bv = Bv[tl];
        #pragma unroll
        for (int r = 0; r < 4; ++r) {
            aq2[r] = (f32x2){bq, 0.f}; ak2[r] = (f32x2){bk, 0.f}; av2[r] = (f32x2){bv, 0.f};
        }
        const float4* Aq4 = (const float4*)(Aq + tl * NDIM);
        const float4* Ak4 = (const float4*)(Ak + tl * NDIM);
        const float4* Av4 = (const float4*)(Av + tl * NDIM);
        #pragma unroll 4
        for (int c = 0; c < NDIM / 4; ++c) {
            const float4 wq = Aq4[c], wk = Ak4[c], wv = Av4[c];
            const f32x2* wqp = (const f32x2*)&wq;
            const f32x2* wkp = (const f32x2*)&wk;
            const f32x2* wvp = (const f32x2*)&wv;
            #pragma unroll
            for (int r = 0; r < 4; ++r) {
                const float4 h4 = *(const float4*)&S.sh[r0 + r][4 * c];
                const f32x2* hp2 = (const f32x2*)&h4;
                aq2[r] = pkfma(wqp[0], hp2[0], aq2[r]);
                aq2[r] = pkfma(wqp[1], hp2[1], aq2[r]);
                ak2[r] = pkfma(wkp[0], hp2[0], ak2[r]);
                ak2[r] = pkfma(wkp[1], hp2[1], ak2[r]);
                av2[r] = pkfma(wvp[0], hp2[0], av2[r]);
                av2[r] = pkfma(wvp[1], hp2[1], av2[r]);
            }
        }
        float kmx[4], kmn[4];
        #pragma unroll
        for (int r = 0; r < 4; ++r) {
            Qp[r] = aq2[r].x + aq2[r].y;
            Kp[r] = ak2[r].x + ak2[r].y;
            Vp[r] = av2[r].x + av2[r].y;
            Qv[r] = siluf(Qp[r]); Kv[r] = siluf(Kp[r]); Vv[r] = siluf(Vp[r]);
            Qe[r] = Qv[r] * LOG2E;
            S.sKVQ[r0 + r][tl] = make_float4(Kv[r], Vv[r], 1.0f, Kv[r] * Vv[r]);
            kmx[r] = Kv[r]; kmn[r] = Kv[r];
        }
        #pragma unroll
        for (int off = 32; off; off >>= 1) {
            #pragma unroll
            for (int r = 0; r < 4; ++r) {
                kmx[r] = fmaxf(kmx[r], __shfl_xor(kmx[r], off));
                kmn[r] = fminf(kmn[r], __shfl_xor(kmn[r], off));
            }
        }
        if ((tid & 63) == 0) {
            #pragma unroll
            for (int r = 0; r < 4; ++r) { S.skmax[wid][r] = kmx[r]; S.skmin[wid][r] = kmn[r]; }
        }
    }
    __syncthreads();

    // ---- C: softmax fwd (+ dQ sums folded), log2 domain; unroll 4 ----
    float mi2[4], rl[4], ti[4], sk[4], skv[4];
    {
        f32x2 st[4], lv[4];   // st = {sk, tn}; lv = {l, skv}
        #pragma unroll
        for (int r = 0; r < 4; ++r) {
            const float kx = fmaxf(S.skmax[2 * tg][r], S.skmax[2 * tg + 1][r]);
            const float kn = fminf(S.skmin[2 * tg][r], S.skmin[2 * tg + 1][r]);
            mi2[r] = fmaxf(Qe[r] * kx, Qe[r] * kn);
            st[r] = (f32x2){0.f, 0.f}; lv[r] = (f32x2){0.f, 0.f};
        }
        __builtin_amdgcn_s_setprio(1);   // exp-dense stage: keep trans pipe fed
        #pragma unroll 4
        for (int j = 0; j < NDIM; ++j) {
            #pragma unroll
            for (int r = 0; r < 4; ++r) {
                const float4 kv4 = S.sKVQ[r0 + r][j];
                const f32x2* kvp = (const f32x2*)&kv4;
                const float e = fexp2(fmaf(Qe[r], kv4.x, -mi2[r]));
                const f32x2 e2 = {e, e};
                st[r] = pkfma(e2, kvp[0], st[r]);
                lv[r] = pkfma(e2, kvp[1], lv[r]);
            }
        }
        __builtin_amdgcn_s_setprio(0);
        #pragma unroll
        for (int r = 0; r < 4; ++r) {
            sk[r] = st[r].x; skv[r] = lv[r].y;
            rl[r] = frcp(lv[r].x);
            ti[r] = st[r].y * rl[r];
            S.sz[r0 + r][tl] = siluf(ti[r]);
        }
    }
    __syncthreads();

    // ---- y = silu(z @ Wout + bout), 8x25 tasks ----
    if (tid < 200) {
        const int r = tid / 25, o = tid - 25 * (tid / 25);
        float a = bout[o];
        #pragma unroll 8
        for (int c = 0; c < NDIM / 4; ++c) {
            const float4 z4 = *(const float4*)&S.sz[r][4 * c];
            a = fmaf(z4.x, Wout[(4 * c + 0) * 25 + o], a);
            a = fmaf(z4.y, Wout[(4 * c + 1) * 25 + o], a);
            a = fmaf(z4.z, Wout[(4 * c + 2) * 25 + o], a);
            a = fmaf(z4.w, Wout[(4 * c + 3) * 25 + o], a);
        }
        S.swp[r][o] = a;
        S.sy[r][o] = siluf(a);
    }
    __syncthreads();

    // ---- backward through the quadratic head ----
    if (tid < 200) {
        const int r = tid / 25, o = tid - 25 * (tid / 25);
        float m11 = 0.f, m12 = 0.f, m21 = 0.f, m22 = 0.f;
        for (int k = 0;  k < 5;  ++k) m11 += S.sy[r][k] * S.sy[r][k];
        for (int k = 5;  k < 10; ++k) m12 += S.sy[r][k] * S.sy[r][k];
        for (int k = 10; k < 15; ++k) m21 += S.sy[r][k] * S.sy[r][k];
        for (int k = 15; k < 20; ++k) m22 += S.sy[r][k] * S.sy[r][k];
        const float q0 = S.sy[r][0], q1 = S.sy[r][1], q2 = S.sy[r][2], q3 = S.sy[r][3];
        const float dm11 = q0 * q0 + q1 * q1;
        const float dm12 = q0 * q2 + q1 * q3;
        const float dm22 = q2 * q2 + q3 * q3;
        float dy;
        if      (o < 5)  dy = 2.0f * S.sy[r][o] * dm11;
        else if (o < 15) dy = 2.0f * S.sy[r][o] * dm12;
        else if (o < 20) dy = 2.0f * S.sy[r][o] * dm22;
        else             dy = 2.0f * S.sy[r][o];
        const float ms = m12 + m21;
        if (o == 0) dy += 2.0f * m11 * q0 + ms * q2;
        if (o == 1) dy += 2.0f * m11 * q1 + ms * q3;
        if (o == 2) dy += ms * q0 + 2.0f * m22 * q2;
        if (o == 3) dy += ms * q1 + 2.0f * m22 * q3;
        S.sdwp[r][o] = dy * dsiluf(S.swp[r][o]);
    }
    __syncthreads();

    // ---- E: dt, closed-form dQ, coefficient pack into sC (2^-m folded) ----
    float dQp_[4];
    {
        float wr[25];
        #pragma unroll
        for (int k = 0; k < 25; ++k) wr[k] = Wout[tl * 25 + k];
        float dt[4] = {0.f, 0.f, 0.f, 0.f};
        #pragma unroll
        for (int k = 0; k < 25; ++k) {
            #pragma unroll
            for (int r = 0; r < 4; ++r)
                dt[r] = fmaf(wr[k], S.sdwp[r0 + r][k], dt[r]);
        }
        #pragma unroll
        for (int r = 0; r < 4; ++r) {
            dt[r] *= dsiluf(ti[r]);
            const float w = dt[r] * rl[r];
            dQp_[r] = (w * fmaf(-ti[r], sk[r], skv[r])) * dsiluf(Qp[r]);
            const float wt = w * fexp2(-mi2[r]);
            const float c1 = wt * Qv[r];
            S.sC[r0 + r][tl] = make_float4(wt, c1, c1 * ti[r], Qe[r]);
        }
    }
    __syncthreads();

    // ---- F: dK_j / dV_j -> sD; packed {accv,k1} pair; unroll 4 ----
    {
        f32x2 vk[4];
        float k2s[4];
        #pragma unroll
        for (int r = 0; r < 4; ++r) { vk[r] = (f32x2){0.f, 0.f}; k2s[r] = 0.f; }
        __builtin_amdgcn_s_setprio(1);   // exp-dense stage
        #pragma unroll 4
        for (int i = 0; i < NDIM; ++i) {
            #pragma unroll
            for (int r = 0; r < 4; ++r) {
                const float4 c4 = S.sC[r0 + r][i];
                const f32x2* cp = (const f32x2*)&c4;
                const float e = fexp2(c4.w * Kv[r]);
                const f32x2 e2 = {e, e};
                vk[r] = pkfma(e2, cp[0], vk[r]);
                k2s[r] = fmaf(e, c4.z, k2s[r]);
            }
        }
        __builtin_amdgcn_s_setprio(0);
        #pragma unroll
        for (int r = 0; r < 4; ++r) {
            const float dVp_ = vk[r].x * dsiluf(Vp[r]);
            const float dKp_ = fmaf(Vv[r], vk[r].y, -k2s[r]) * dsiluf(Kp[r]);
            S.sD[r0 + r][tl] = make_float4(dQp_[r], dKp_, dVp_, 0.f);
        }
    }
    __syncthreads();

    // ---- G: dh_d = sum_i Aq[i][d]dQp + Ak[i][d]dKp + Av[i][d]dVp; unroll 8 ----
    float dhp[4];
    {
        float acc[4] = {0.f, 0.f, 0.f, 0.f};
        #pragma unroll 8
        for (int i = 0; i < NDIM; ++i) {
            const float aqv = Aq[i * NDIM + tl];
            const float akv = Ak[i * NDIM + tl];
            const float avv = Av[i * NDIM + tl];
            #pragma unroll
            for (int r = 0; r < 4; ++r) {
                const float4 d4 = S.sD[r0 + r][i];
                acc[r] = fmaf(aqv, d4.x, acc[r]);
                acc[r] = fmaf(akv, d4.y, acc[r]);
                acc[r] = fmaf(avv, d4.z, acc[r]);
            }
        }
        #pragma unroll
        for (int r = 0; r < 4; ++r) dhp[r] = acc[r] * dsiluf(hp[r]);
    }

    // ---- dx_o (o=0,1): shuffle reduce per row, cross-wave combine ----
    {
        const float w0 = Win[tl], w1 = Win[NDIM + tl];
        float t0[4], t1[4];
        #pragma unroll
        for (int r = 0; r < 4; ++r) { t0[r] = w0 * dhp[r]; t1[r] = w1 * dhp[r]; }
        #pragma unroll
        for (int off = 32; off; off >>= 1) {
            #pragma unroll
            for (int r = 0; r < 4; ++r) {
                t0[r] += __shfl_xor(t0[r], off);
                t1[r] += __shfl_xor(t1[r], off);
            }
        }
        if ((tid & 63) == 0) {
            #pragma unroll
            for (int r = 0; r < 4; ++r) { S.sred[wid][r][0] = t0[r]; S.sred[wid][r][1] = t1[r]; }
        }
    }
    __syncthreads();
    if (tid < 16) {
        const int o = tid >> 3, ag = tid & 7;
        const int gg = ag >> 2, rr = ag & 3;
        sdHf[o * 8 + ag] = S.sred[2 * gg][rr][o] + S.sred[2 * gg + 1][rr][o];
    }
    // caller issues the inter-phase __syncthreads()
}

// ---------------------------------------------------------------------------
// Phase 2: J + R forwards + assembly. Round-11 configuration (JR-B unroll 2,
// JR-C 4, JR-D 8) + s_setprio(1) around the exp-dense attention loop.
// ---------------------------------------------------------------------------
__device__ __forceinline__ void jr_path(
    int b, int tid, JRS& S,
    const float* __restrict__ JWin, const float* __restrict__ Jbin,
    const float* __restrict__ JAq, const float* __restrict__ JAk, const float* __restrict__ JAv,
    const float* __restrict__ JBq, const float* __restrict__ JBk, const float* __restrict__ JBv,
    const float* __restrict__ JWout, const float* __restrict__ Jbout,
    const float* __restrict__ RWin, const float* __restrict__ Rbin,
    const float* __restrict__ RAq, const float* __restrict__ RAk, const float* __restrict__ RAv,
    const float* __restrict__ RBq, const float* __restrict__ RBk, const float* __restrict__ RBv,
    const float* __restrict__ RWout, const float* __restrict__ Rbout,
    const float* sdHf, double* sdH, double* sg, double (*sRm)[17],
    double* srs, double* svv, float* sJvp,
    float* __restrict__ out)
{
    const int g  = tid >> 7;
    const int tl = tid & 127;
    const int wg = (tid >> 6) & 1;

    if (tid < 16) sdH[tid] = (double)sdHf[tid];   // consumed much later

    const float* Win  = g ? RWin  : JWin;
    const float* bin_ = g ? Rbin  : Jbin;
    const float* Aq   = g ? RAq   : JAq;
    const float* Ak   = g ? RAk   : JAk;
    const float* Av   = g ? RAv   : JAv;
    const float* Bq   = g ? RBq   : JBq;
    const float* Bk   = g ? RBk   : JBk;
    const float* Bv   = g ? RBv   : JBv;

    // ---- A: h[a][tl] for all 8 agents (x already in S.sx) ----
    {
        float acc[8];
        const float b0 = bin_[tl];
        #pragma unroll
        for (int a = 0; a < 8; ++a) acc[a] = b0;
        #pragma unroll
        for (int c = 0; c < 4; ++c) {
            const float w0 = Win[(4 * c + 0) * NDIM + tl];
            const float w1 = Win[(4 * c + 1) * NDIM + tl];
            const float w2 = Win[(4 * c + 2) * NDIM + tl];
            const float w3 = Win[(4 * c + 3) * NDIM + tl];
            #pragma unroll
            for (int a = 0; a < 8; ++a) {
                const float4 x4 = *(const float4*)&S.sx[a * 16 + 4 * c];
                acc[a] = fmaf(w0, x4.x, acc[a]);
                acc[a] = fmaf(w1, x4.y, acc[a]);
                acc[a] = fmaf(w2, x4.z, acc[a]);
                acc[a] = fmaf(w3, x4.w, acc[a]);
            }
        }
        *(float4*)&S.sh[g][tl][0] =
            make_float4(siluf(acc[0]), siluf(acc[1]), siluf(acc[2]), siluf(acc[3]));
        *(float4*)&S.sh[g][tl][4] =
            make_float4(siluf(acc[4]), siluf(acc[5]), siluf(acc[6]), siluf(acc[7]));
    }
    __syncthreads();

    // ---- B: Q,K,V for all 8 agents; packed agent-pairs; unroll 2 ----
    f32x2 qe2[4];
    {
        f32x2 aq2[4], ak2[4], av2[4];
        const float bq = Bq[tl], bk = Bk[tl], bv = Bv[tl];
        #pragma unroll
        for (int p = 0; p < 4; ++p) {
            aq2[p] = (f32x2){bq, bq}; ak2[p] = (f32x2){bk, bk}; av2[p] = (f32x2){bv, bv};
        }
        const float4* Aq4 = (const float4*)(Aq + tl * NDIM);
        const float4* Ak4 = (const float4*)(Ak + tl * NDIM);
        const float4* Av4 = (const float4*)(Av + tl * NDIM);
        #pragma unroll 2
        for (int c = 0; c < NDIM / 4; ++c) {
            const float4 wq = Aq4[c], wk = Ak4[c], wv = Av4[c];
            const float wqa[4] = {wq.x, wq.y, wq.z, wq.w};
            const float wka[4] = {wk.x, wk.y, wk.z, wk.w};
            const float wva[4] = {wv.x, wv.y, wv.z, wv.w};
            #pragma unroll
            for (int jj = 0; jj < 4; ++jj) {
                const float4 h0 = *(const float4*)&S.sh[g][4 * c + jj][0];
                const float4 h1 = *(const float4*)&S.sh[g][4 * c + jj][4];
                const f32x2* h0p = (const f32x2*)&h0;
                const f32x2* h1p = (const f32x2*)&h1;
                const f32x2 qq = {wqa[jj], wqa[jj]};
                const f32x2 kk2 = {wka[jj], wka[jj]};
                const f32x2 vv2 = {wva[jj], wva[jj]};
                aq2[0] = pkfma(qq, h0p[0], aq2[0]); aq2[1] = pkfma(qq, h0p[1], aq2[1]);
                aq2[2] = pkfma(qq, h1p[0], aq2[2]); aq2[3] = pkfma(qq, h1p[1], aq2[3]);
                ak2[0] = pkfma(kk2, h0p[0], ak2[0]); ak2[1] = pkfma(kk2, h0p[1], ak2[1]);
                ak2[2] = pkfma(kk2, h1p[0], ak2[2]); ak2[3] = pkfma(kk2, h1p[1], ak2[3]);
                av2[0] = pkfma(vv2, h0p[0], av2[0]); av2[1] = pkfma(vv2, h0p[1], av2[1]);
                av2[2] = pkfma(vv2, h1p[0], av2[2]); av2[3] = pkfma(vv2, h1p[1], av2[3]);
            }
        }
        float kk[8], kx[8], kn[8];
        #pragma unroll
        for (int s = 0; s < 8; ++s) {
            const int p = s >> 1, e = s & 1;
            qe2[p][e] = siluf(aq2[p][e]) * LOG2E;
            kk[s] = siluf(ak2[p][e]);
            S.sK[g][tl][s] = kk[s];
            S.sV[g][tl][s] = siluf(av2[p][e]);
            kx[s] = kk[s]; kn[s] = kk[s];
        }
        #pragma unroll
        for (int off = 32; off; off >>= 1) {
            #pragma unroll
            for (int s = 0; s < 8; ++s) {
                kx[s] = fmaxf(kx[s], __shfl_xor(kx[s], off));
                kn[s] = fminf(kn[s], __shfl_xor(kn[s], off));
            }
        }
        if ((tid & 63) == 0) {
            #pragma unroll
            for (int s = 0; s < 8; ++s) { S.skr[g][wg][0][s] = kx[s]; S.skr[g][wg][1][s] = kn[s]; }
        }
    }
    __syncthreads();

    // ---- C: attention row tl, single pass, global-bound shift; unroll 4 ----
    {
        float bnd2 = 0.f;
        #pragma unroll
        for (int s = 0; s < 8; ++s) {
            const float kx = fmaxf(S.skr[g][0][0][s], S.skr[g][1][0][s]);
            const float kn = fminf(S.skr[g][0][1][s], S.skr[g][1][1][s]);
            const float q = qe2[s >> 1][s & 1];
            bnd2 += fmaxf(q * kx, q * kn);
        }
        float l = 0.f;
        f32x2 t2[4];
        #pragma unroll
        for (int p = 0; p < 4; ++p) t2[p] = (f32x2){0.f, 0.f};
        __builtin_amdgcn_s_setprio(1);   // exp-dense stage
        #pragma unroll 4
        for (int j = 0; j < NDIM; ++j) {
            const float4 k0 = *(const float4*)&S.sK[g][j][0];
            const float4 k1 = *(const float4*)&S.sK[g][j][4];
            const f32x2* k0p = (const f32x2*)&k0;
            const f32x2* k1p = (const f32x2*)&k1;
            f32x2 d2 = {-bnd2, 0.f};
            d2 = pkfma(qe2[0], k0p[0], d2);
            d2 = pkfma(qe2[1], k0p[1], d2);
            d2 = pkfma(qe2[2], k1p[0], d2);
            d2 = pkfma(qe2[3], k1p[1], d2);
            const float e = fexp2(d2.x + d2.y);
            const float4 v0 = *(const float4*)&S.sV[g][j][0];
            const float4 v1 = *(const float4*)&S.sV[g][j][4];
            const f32x2* v0p = (const f32x2*)&v0;
            const f32x2* v1p = (const f32x2*)&v1;
            const f32x2 e2 = {e, e};
            l += e;
            t2[0] = pkfma(e2, v0p[0], t2[0]);
            t2[1] = pkfma(e2, v0p[1], t2[1]);
            t2[2] = pkfma(e2, v1p[0], t2[2]);
            t2[3] = pkfma(e2, v1p[1], t2[3]);
        }
        __builtin_amdgcn_s_setprio(0);
        const float rl = frcp(l);
        #pragma unroll
        for (int s = 0; s < 8; ++s)
            S.sz[g][s][tl] = siluf(t2[s >> 1][s & 1] * rl);
    }
    __syncthreads();

    // ---- D: w[s,o] = silu(z @ Wout + bout). R on tids 0-127, J on 128-191 ----
    if (tid < 192) {
        const int gm = (tid < 128) ? 1 : 0;
        const int t2 = (tid < 128) ? tid : tid - 128;
        const int lo2 = gm ? 4 : 3;
        const int outd = 1 << lo2;
        const int s = t2 >> lo2, o = t2 & (outd - 1);
        const float* Wo = gm ? RWout : JWout;
        const float* bo = gm ? Rbout : Jbout;
        float a = bo[o];
        #pragma unroll 8
        for (int c = 0; c < NDIM / 4; ++c) {
            const float4 z4 = *(const float4*)&S.sz[gm][s][4 * c];
            a = fmaf(z4.x, Wo[(4 * c + 0) * outd + o], a);
            a = fmaf(z4.y, Wo[(4 * c + 1) * outd + o], a);
            a = fmaf(z4.z, Wo[(4 * c + 2) * outd + o], a);
            a = fmaf(z4.w, Wo[(4 * c + 3) * outd + o], a);
        }
        S.sw[gm][t2] = siluf(a);
    }
    __syncthreads();

    // ---- J scalar + R group sums ----
    if (tid < 64) {
        float v = S.sw[0][tid];
        #pragma unroll
        for (int off = 32; off; off >>= 1) v += __shfl_xor(v, off);
        if (tid == 0) *sJvp = v;
    } else if (tid < 96) {
        const int t = tid - 64, pq = t >> 3, c = t & 7;
        const int base = c * 16 + pq * 4;
        sg[t] = (double)S.sw[1][base] + (double)S.sw[1][base + 1]
              + (double)S.sw[1][base + 2] + (double)S.sw[1][base + 3];
    }
    __syncthreads();

    // ---- assembly: Rupper, Laplacian Rm, u = (J_eff - Rm Rm^T) dH ----
    const int ii = (tid >> 4) & 15, jj = tid & 15;
    {
        const double rij = sg[((ii >> 3) * 2 + (jj >> 3)) * 8 + (jj & 7)];
        const double rji = sg[((jj >> 3) * 2 + (ii >> 3)) * 8 + (ii & 7)];
        sRm[ii][jj] = rij * rij + rji * rji;
    }
    __syncthreads();

    if (tid < 16) {
        double a = 0.0;
        for (int j = 0; j < 16; ++j) a += sRm[tid][j];
        srs[tid] = a;
    }
    __syncthreads();

    {
        const double v = (ii == jj) ? srs[ii] : -sRm[ii][jj];
        __syncthreads();
        sRm[ii][jj] = v;
    }
    __syncthreads();

    if (tid < 16) {
        double a = 0.0;
        for (int j = 0; j < 16; ++j) a += sRm[tid][j] * sdH[j];
        svv[tid] = a;
    }
    __syncthreads();

    if (tid < 16) {
        double a = 0.0;
        for (int k = 0; k < 16; ++k) a += sRm[tid][k] * svv[k];
        const double sj = (double)(*sJvp);
        const double jterm = (tid < 8) ? 2.0 * sj * sdH[8 + tid]
                                       : -2.0 * sj * sdH[tid - 8];
        out[b * 16 + tid] = (float)(jterm - a);
    }
}

// ---------------------------------------------------------------------------
// One kernel, one block per batch: H phase -> LDS handoff -> JR phase.
// ---------------------------------------------------------------------------
__global__ __launch_bounds__(256) void k_all(
    const float* __restrict__ x,
    const float* __restrict__ HWin, const float* __restrict__ Hbin,
    const float* __restrict__ HAq, const float* __restrict__ HAk, const float* __restrict__ HAv,
    const float* __restrict__ HBq, const float* __restrict__ HBk, const float* __restrict__ HBv,
    const float* __restrict__ HWout, const float* __restrict__ Hbout,
    const float* __restrict__ JWin, const float* __restrict__ Jbin,
    const float* __restrict__ JAq, const float* __restrict__ JAk, const float* __restrict__ JAv,
    const float* __restrict__ JBq, const float* __restrict__ JBk, const float* __restrict__ JBv,
    const float* __restrict__ JWout, const float* __restrict__ Jbout,
    const float* __restrict__ RWin, const float* __restrict__ Rbin,
    const float* __restrict__ RAq, const float* __restrict__ RAk, const float* __restrict__ RAv,
    const float* __restrict__ RBq, const float* __restrict__ RBk, const float* __restrict__ RBv,
    const float* __restrict__ RWout, const float* __restrict__ Rbout,
    float* __restrict__ out)
{
    __shared__ SU S;
    __shared__ float  sdHf[16];
    __shared__ float  sJv;
    __shared__ double sdH[16], sg[32], sRm[16][17], srs[16], svv[16];

    const int b = blockIdx.x;

    h_path(b, threadIdx.x, S.h, x, HWin, Hbin, HAq, HAk, HAv,
           HBq, HBk, HBv, HWout, Hbout, sdHf);
    __syncthreads();   // inter-phase: sdHf visible; HS buffers dead

    jr_path(b, threadIdx.x, S.jr,
            JWin, Jbin, JAq, JAk, JAv, JBq, JBk, JBv, JWout, Jbout,
            RWin, Rbin, RAq, RAk, RAv, RBq, RBk, RBv, RWout, Rbout,
            sdHf, sdH, sg, sRm, srs, svv, &sJv, out);
}

// ---------------------------------------------------------------------------
extern "C" void kernel_launch(void* const* d_in, const int* in_sizes, int n_in,
                              void* d_out, int out_size, void* d_ws, size_t ws_size,
                              hipStream_t stream)
{
    const float* x = (const float*)d_in[0];
    float* out = (float*)d_out;

#define ARGS10(base) \
    (const float*)d_in[(base) + 0], (const float*)d_in[(base) + 1], \
    (const float*)d_in[(base) + 2], (const float*)d_in[(base) + 3], \
    (const float*)d_in[(base) + 4], (const float*)d_in[(base) + 5], \
    (const float*)d_in[(base) + 6], (const float*)d_in[(base) + 7], \
    (const float*)d_in[(base) + 8], (const float*)d_in[(base) + 9]

    k_all<<<dim3(512), dim3(256), 0, stream>>>(
        x, ARGS10(1), ARGS10(11), ARGS10(21), out);
#undef ARGS10
}

// Round 15
// 111.160 us; speedup vs baseline: 1.0358x; 1.0358x over previous
//
#include <hip/hip_runtime.h>

#define NDIM 128
#define NOBS 16
#define LOG2E 1.44269504088896341f

typedef float f32x2 __attribute__((ext_vector_type(2)));

__device__ __forceinline__ float frcp(float x) { return __builtin_amdgcn_rcpf(x); }
__device__ __forceinline__ float fexp2(float x) { return __builtin_amdgcn_exp2f(x); }
__device__ __forceinline__ float fexp(float x) { return __builtin_amdgcn_exp2f(x * LOG2E); }
__device__ __forceinline__ float sigf(float v) { return frcp(1.0f + fexp(-v)); }
__device__ __forceinline__ float siluf(float v) { return v * sigf(v); }
__device__ __forceinline__ float dsiluf(float v) {
    float s = sigf(v);
    return s * (1.0f + v * (1.0f - s));
}
__device__ __forceinline__ f32x2 pkfma(f32x2 a, f32x2 b, f32x2 c) {
    return __builtin_elementwise_fma(a, b, c);
}

// ---- LDS layouts: both phases union into one 60.6 KB block ----------------
// Both structs BEGIN with the identical 512-byte x image, so x loaded in the
// H phase persists into the JR phase (no H-phase field aliases offset 0-511).
struct HS {
    float  sx[8][NOBS];
    float  sh[8][NDIM];
    float4 sKVQ[8][NDIM];   // {K, V, 1.0, K*V}
    float  sz[8][NDIM];
    float4 sC[8][NDIM];     // {wt, wt*Q, wt*Q*t, Qe}
    float4 sD[8][NDIM];     // {dQp, dKp, dVp, 0}
    float  sy[8][26], swp[8][26], sdwp[8][26];
    float  skmax[4][4], skmin[4][4];
    float  sred[4][4][2];
};
struct JRS {
    float sx[128];          // aliases HS::sx — same linear layout
    float sh[2][NDIM][8];
    float sK[2][NDIM][8];
    float sV[2][NDIM][8];
    float sz[2][8][132];
    float sw[2][NDIM];
    float skr[2][2][2][8];
};
union SU { HS h; JRS jr; };

// ---------------------------------------------------------------------------
// Phase 1: H-module gradient for one batch (8 rows). Round-11 configuration:
// unrolls B/C/F: 4, G: 8 (VGPR sweet spot just under the 128 boundary).
// ---------------------------------------------------------------------------
__device__ __forceinline__ void h_path(
    int b, int tid, HS& S,
    const float* __restrict__ x,
    const float* __restrict__ Win, const float* __restrict__ bin,
    const float* __restrict__ Aq, const float* __restrict__ Ak, const float* __restrict__ Av,
    const float* __restrict__ Bq, const float* __restrict__ Bk, const float* __restrict__ Bv,
    const float* __restrict__ Wout, const float* __restrict__ bout,
    float* sdHf)
{
    const int tl = tid & 127, tg = tid >> 7, wid = tid >> 6, r0 = tg * 4;

    if (tid < 128) S.sx[tid >> 4][tid & 15] = x[b * 128 + tid];
    __syncthreads();

    // ---- A: h = silu(x @ Win + bin) ----
    float hp[4];
    {
        float acc[4];
        const float b0 = bin[tl];
        #pragma unroll
        for (int r = 0; r < 4; ++r) acc[r] = b0;
        #pragma unroll
        for (int o = 0; o < NOBS; ++o) {
            const float w = Win[o * NDIM + tl];
            #pragma unroll
            for (int r = 0; r < 4; ++r) acc[r] = fmaf(w, S.sx[r0 + r][o], acc[r]);
        }
        #pragma unroll
        for (int r = 0; r < 4; ++r) { hp[r] = acc[r]; S.sh[r0 + r][tl] = siluf(acc[r]); }
    }
    __syncthreads();

    // ---- B: Q,K,V = silu(A h + B); packed pairs; unroll 4 ----
    float Qp[4], Kp[4], Vp[4], Qv[4], Kv[4], Vv[4], Qe[4];
    {
        f32x2 aq2[4], ak2[4], av2[4];
        const float bq = Bq[tl], bk = Bk[tl], bv = Bv[tl];
        #pragma unroll
        for (int r = 0; r < 4; ++r) {
            aq2[r] = (f32x2){bq, 0.f}; ak2[r] = (f32x2){bk, 0.f}; av2[r] = (f32x2){bv, 0.f};
        }
        const float4* Aq4 = (const float4*)(Aq + tl * NDIM);
        const float4* Ak4 = (const float4*)(Ak + tl * NDIM);
        const float4* Av4 = (const float4*)(Av + tl * NDIM);
        #pragma unroll 4
        for (int c = 0; c < NDIM / 4; ++c) {
            const float4 wq = Aq4[c], wk = Ak4[c], wv = Av4[c];
            const f32x2* wqp = (const f32x2*)&wq;
            const f32x2* wkp = (const f32x2*)&wk;
            const f32x2* wvp = (const f32x2*)&wv;
            #pragma unroll
            for (int r = 0; r < 4; ++r) {
                const float4 h4 = *(const float4*)&S.sh[r0 + r][4 * c];
                const f32x2* hp2 = (const f32x2*)&h4;
                aq2[r] = pkfma(wqp[0], hp2[0], aq2[r]);
                aq2[r] = pkfma(wqp[1], hp2[1], aq2[r]);
                ak2[r] = pkfma(wkp[0], hp2[0], ak2[r]);
                ak2[r] = pkfma(wkp[1], hp2[1], ak2[r]);
                av2[r] = pkfma(wvp[0], hp2[0], av2[r]);
                av2[r] = pkfma(wvp[1], hp2[1], av2[r]);
            }
        }
        float kmx[4], kmn[4];
        #pragma unroll
        for (int r = 0; r < 4; ++r) {
            Qp[r] = aq2[r].x + aq2[r].y;
            Kp[r] = ak2[r].x + ak2[r].y;
            Vp[r] = av2[r].x + av2[r].y;
            Qv[r] = siluf(Qp[r]); Kv[r] = siluf(Kp[r]); Vv[r] = siluf(Vp[r]);
            Qe[r] = Qv[r] * LOG2E;
            S.sKVQ[r0 + r][tl] = make_float4(Kv[r], Vv[r], 1.0f, Kv[r] * Vv[r]);
            kmx[r] = Kv[r]; kmn[r] = Kv[r];
        }
        #pragma unroll
        for (int off = 32; off; off >>= 1) {
            #pragma unroll
            for (int r = 0; r < 4; ++r) {
                kmx[r] = fmaxf(kmx[r], __shfl_xor(kmx[r], off));
                kmn[r] = fminf(kmn[r], __shfl_xor(kmn[r], off));
            }
        }
        if ((tid & 63) == 0) {
            #pragma unroll
            for (int r = 0; r < 4; ++r) { S.skmax[wid][r] = kmx[r]; S.skmin[wid][r] = kmn[r]; }
        }
    }
    __syncthreads();

    // ---- C: softmax fwd (+ dQ sums folded), log2 domain; unroll 4 ----
    float mi2[4], rl[4], ti[4], sk[4], skv[4];
    {
        f32x2 st[4], lv[4];   // st = {sk, tn}; lv = {l, skv}
        #pragma unroll
        for (int r = 0; r < 4; ++r) {
            const float kx = fmaxf(S.skmax[2 * tg][r], S.skmax[2 * tg + 1][r]);
            const float kn = fminf(S.skmin[2 * tg][r], S.skmin[2 * tg + 1][r]);
            mi2[r] = fmaxf(Qe[r] * kx, Qe[r] * kn);
            st[r] = (f32x2){0.f, 0.f}; lv[r] = (f32x2){0.f, 0.f};
        }
        #pragma unroll 4
        for (int j = 0; j < NDIM; ++j) {
            #pragma unroll
            for (int r = 0; r < 4; ++r) {
                const float4 kv4 = S.sKVQ[r0 + r][j];
                const f32x2* kvp = (const f32x2*)&kv4;
                const float e = fexp2(fmaf(Qe[r], kv4.x, -mi2[r]));
                const f32x2 e2 = {e, e};
                st[r] = pkfma(e2, kvp[0], st[r]);
                lv[r] = pkfma(e2, kvp[1], lv[r]);
            }
        }
        #pragma unroll
        for (int r = 0; r < 4; ++r) {
            sk[r] = st[r].x; skv[r] = lv[r].y;
            rl[r] = frcp(lv[r].x);
            ti[r] = st[r].y * rl[r];
            S.sz[r0 + r][tl] = siluf(ti[r]);
        }
    }
    __syncthreads();

    // ---- y = silu(z @ Wout + bout), 8x25 tasks ----
    if (tid < 200) {
        const int r = tid / 25, o = tid - 25 * (tid / 25);
        float a = bout[o];
        #pragma unroll 8
        for (int c = 0; c < NDIM / 4; ++c) {
            const float4 z4 = *(const float4*)&S.sz[r][4 * c];
            a = fmaf(z4.x, Wout[(4 * c + 0) * 25 + o], a);
            a = fmaf(z4.y, Wout[(4 * c + 1) * 25 + o], a);
            a = fmaf(z4.z, Wout[(4 * c + 2) * 25 + o], a);
            a = fmaf(z4.w, Wout[(4 * c + 3) * 25 + o], a);
        }
        S.swp[r][o] = a;
        S.sy[r][o] = siluf(a);
    }
    __syncthreads();

    // ---- backward through the quadratic head ----
    if (tid < 200) {
        const int r = tid / 25, o = tid - 25 * (tid / 25);
        float m11 = 0.f, m12 = 0.f, m21 = 0.f, m22 = 0.f;
        for (int k = 0;  k < 5;  ++k) m11 += S.sy[r][k] * S.sy[r][k];
        for (int k = 5;  k < 10; ++k) m12 += S.sy[r][k] * S.sy[r][k];
        for (int k = 10; k < 15; ++k) m21 += S.sy[r][k] * S.sy[r][k];
        for (int k = 15; k < 20; ++k) m22 += S.sy[r][k] * S.sy[r][k];
        const float q0 = S.sy[r][0], q1 = S.sy[r][1], q2 = S.sy[r][2], q3 = S.sy[r][3];
        const float dm11 = q0 * q0 + q1 * q1;
        const float dm12 = q0 * q2 + q1 * q3;
        const float dm22 = q2 * q2 + q3 * q3;
        float dy;
        if      (o < 5)  dy = 2.0f * S.sy[r][o] * dm11;
        else if (o < 15) dy = 2.0f * S.sy[r][o] * dm12;
        else if (o < 20) dy = 2.0f * S.sy[r][o] * dm22;
        else             dy = 2.0f * S.sy[r][o];
        const float ms = m12 + m21;
        if (o == 0) dy += 2.0f * m11 * q0 + ms * q2;
        if (o == 1) dy += 2.0f * m11 * q1 + ms * q3;
        if (o == 2) dy += ms * q0 + 2.0f * m22 * q2;
        if (o == 3) dy += ms * q1 + 2.0f * m22 * q3;
        S.sdwp[r][o] = dy * dsiluf(S.swp[r][o]);
    }
    __syncthreads();

    // ---- E: dt, closed-form dQ, coefficient pack into sC (2^-m folded) ----
    float dQp_[4];
    {
        float wr[25];
        #pragma unroll
        for (int k = 0; k < 25; ++k) wr[k] = Wout[tl * 25 + k];
        float dt[4] = {0.f, 0.f, 0.f, 0.f};
        #pragma unroll
        for (int k = 0; k < 25; ++k) {
            #pragma unroll
            for (int r = 0; r < 4; ++r)
                dt[r] = fmaf(wr[k], S.sdwp[r0 + r][k], dt[r]);
        }
        #pragma unroll
        for (int r = 0; r < 4; ++r) {
            dt[r] *= dsiluf(ti[r]);
            const float w = dt[r] * rl[r];
            dQp_[r] = (w * fmaf(-ti[r], sk[r], skv[r])) * dsiluf(Qp[r]);
            const float wt = w * fexp2(-mi2[r]);
            const float c1 = wt * Qv[r];
            S.sC[r0 + r][tl] = make_float4(wt, c1, c1 * ti[r], Qe[r]);
        }
    }
    __syncthreads();

    // ---- F: dK_j / dV_j -> sD; packed {accv,k1} pair; unroll 4 ----
    {
        f32x2 vk[4];
        float k2s[4];
        #pragma unroll
        for (int r = 0; r < 4; ++r) { vk[r] = (f32x2){0.f, 0.f}; k2s[r] = 0.f; }
        #pragma unroll 4
        for (int i = 0; i < NDIM; ++i) {
            #pragma unroll
            for (int r = 0; r < 4; ++r) {
                const float4 c4 = S.sC[r0 + r][i];
                const f32x2* cp = (const f32x2*)&c4;
                const float e = fexp2(c4.w * Kv[r]);
                const f32x2 e2 = {e, e};
                vk[r] = pkfma(e2, cp[0], vk[r]);
                k2s[r] = fmaf(e, c4.z, k2s[r]);
            }
        }
        #pragma unroll
        for (int r = 0; r < 4; ++r) {
            const float dVp_ = vk[r].x * dsiluf(Vp[r]);
            const float dKp_ = fmaf(Vv[r], vk[r].y, -k2s[r]) * dsiluf(Kp[r]);
            S.sD[r0 + r][tl] = make_float4(dQp_[r], dKp_, dVp_, 0.f);
        }
    }
    __syncthreads();

    // ---- G: dh_d = sum_i Aq[i][d]dQp + Ak[i][d]dKp + Av[i][d]dVp; unroll 8 ----
    float dhp[4];
    {
        float acc[4] = {0.f, 0.f, 0.f, 0.f};
        #pragma unroll 8
        for (int i = 0; i < NDIM; ++i) {
            const float aqv = Aq[i * NDIM + tl];
            const float akv = Ak[i * NDIM + tl];
            const float avv = Av[i * NDIM + tl];
            #pragma unroll
            for (int r = 0; r < 4; ++r) {
                const float4 d4 = S.sD[r0 + r][i];
                acc[r] = fmaf(aqv, d4.x, acc[r]);
                acc[r] = fmaf(akv, d4.y, acc[r]);
                acc[r] = fmaf(avv, d4.z, acc[r]);
            }
        }
        #pragma unroll
        for (int r = 0; r < 4; ++r) dhp[r] = acc[r] * dsiluf(hp[r]);
    }

    // ---- dx_o (o=0,1): shuffle reduce per row, cross-wave combine ----
    {
        const float w0 = Win[tl], w1 = Win[NDIM + tl];
        float t0[4], t1[4];
        #pragma unroll
        for (int r = 0; r < 4; ++r) { t0[r] = w0 * dhp[r]; t1[r] = w1 * dhp[r]; }
        #pragma unroll
        for (int off = 32; off; off >>= 1) {
            #pragma unroll
            for (int r = 0; r < 4; ++r) {
                t0[r] += __shfl_xor(t0[r], off);
                t1[r] += __shfl_xor(t1[r], off);
            }
        }
        if ((tid & 63) == 0) {
            #pragma unroll
            for (int r = 0; r < 4; ++r) { S.sred[wid][r][0] = t0[r]; S.sred[wid][r][1] = t1[r]; }
        }
    }
    __syncthreads();
    if (tid < 16) {
        const int o = tid >> 3, ag = tid & 7;
        const int gg = ag >> 2, rr = ag & 3;
        sdHf[o * 8 + ag] = S.sred[2 * gg][rr][o] + S.sred[2 * gg + 1][rr][o];
    }
    // caller issues the inter-phase __syncthreads()
}

// ---------------------------------------------------------------------------
// Phase 2: J + R forwards + assembly. Round-11 configuration: JR-B unroll 2,
// JR-C 4, JR-D 8.
// ---------------------------------------------------------------------------
__device__ __forceinline__ void jr_path(
    int b, int tid, JRS& S,
    const float* __restrict__ JWin, const float* __restrict__ Jbin,
    const float* __restrict__ JAq, const float* __restrict__ JAk, const float* __restrict__ JAv,
    const float* __restrict__ JBq, const float* __restrict__ JBk, const float* __restrict__ JBv,
    const float* __restrict__ JWout, const float* __restrict__ Jbout,
    const float* __restrict__ RWin, const float* __restrict__ Rbin,
    const float* __restrict__ RAq, const float* __restrict__ RAk, const float* __restrict__ RAv,
    const float* __restrict__ RBq, const float* __restrict__ RBk, const float* __restrict__ RBv,
    const float* __restrict__ RWout, const float* __restrict__ Rbout,
    const float* sdHf, double* sdH, double* sg, double (*sRm)[17],
    double* srs, double* svv, float* sJvp,
    float* __restrict__ out)
{
    const int g  = tid >> 7;
    const int tl = tid & 127;
    const int wg = (tid >> 6) & 1;

    if (tid < 16) sdH[tid] = (double)sdHf[tid];   // consumed much later

    const float* Win  = g ? RWin  : JWin;
    const float* bin_ = g ? Rbin  : Jbin;
    const float* Aq   = g ? RAq   : JAq;
    const float* Ak   = g ? RAk   : JAk;
    const float* Av   = g ? RAv   : JAv;
    const float* Bq   = g ? RBq   : JBq;
    const float* Bk   = g ? RBk   : JBk;
    const float* Bv   = g ? RBv   : JBv;

    // ---- A: h[a][tl] for all 8 agents (x already in S.sx) ----
    {
        float acc[8];
        const float b0 = bin_[tl];
        #pragma unroll
        for (int a = 0; a < 8; ++a) acc[a] = b0;
        #pragma unroll
        for (int c = 0; c < 4; ++c) {
            const float w0 = Win[(4 * c + 0) * NDIM + tl];
            const float w1 = Win[(4 * c + 1) * NDIM + tl];
            const float w2 = Win[(4 * c + 2) * NDIM + tl];
            const float w3 = Win[(4 * c + 3) * NDIM + tl];
            #pragma unroll
            for (int a = 0; a < 8; ++a) {
                const float4 x4 = *(const float4*)&S.sx[a * 16 + 4 * c];
                acc[a] = fmaf(w0, x4.x, acc[a]);
                acc[a] = fmaf(w1, x4.y, acc[a]);
                acc[a] = fmaf(w2, x4.z, acc[a]);
                acc[a] = fmaf(w3, x4.w, acc[a]);
            }
        }
        *(float4*)&S.sh[g][tl][0] =
            make_float4(siluf(acc[0]), siluf(acc[1]), siluf(acc[2]), siluf(acc[3]));
        *(float4*)&S.sh[g][tl][4] =
            make_float4(siluf(acc[4]), siluf(acc[5]), siluf(acc[6]), siluf(acc[7]));
    }
    __syncthreads();

    // ---- B: Q,K,V for all 8 agents; packed agent-pairs; unroll 2 ----
    f32x2 qe2[4];
    {
        f32x2 aq2[4], ak2[4], av2[4];
        const float bq = Bq[tl], bk = Bk[tl], bv = Bv[tl];
        #pragma unroll
        for (int p = 0; p < 4; ++p) {
            aq2[p] = (f32x2){bq, bq}; ak2[p] = (f32x2){bk, bk}; av2[p] = (f32x2){bv, bv};
        }
        const float4* Aq4 = (const float4*)(Aq + tl * NDIM);
        const float4* Ak4 = (const float4*)(Ak + tl * NDIM);
        const float4* Av4 = (const float4*)(Av + tl * NDIM);
        #pragma unroll 2
        for (int c = 0; c < NDIM / 4; ++c) {
            const float4 wq = Aq4[c], wk = Ak4[c], wv = Av4[c];
            const float wqa[4] = {wq.x, wq.y, wq.z, wq.w};
            const float wka[4] = {wk.x, wk.y, wk.z, wk.w};
            const float wva[4] = {wv.x, wv.y, wv.z, wv.w};
            #pragma unroll
            for (int jj = 0; jj < 4; ++jj) {
                const float4 h0 = *(const float4*)&S.sh[g][4 * c + jj][0];
                const float4 h1 = *(const float4*)&S.sh[g][4 * c + jj][4];
                const f32x2* h0p = (const f32x2*)&h0;
                const f32x2* h1p = (const f32x2*)&h1;
                const f32x2 qq = {wqa[jj], wqa[jj]};
                const f32x2 kk2 = {wka[jj], wka[jj]};
                const f32x2 vv2 = {wva[jj], wva[jj]};
                aq2[0] = pkfma(qq, h0p[0], aq2[0]); aq2[1] = pkfma(qq, h0p[1], aq2[1]);
                aq2[2] = pkfma(qq, h1p[0], aq2[2]); aq2[3] = pkfma(qq, h1p[1], aq2[3]);
                ak2[0] = pkfma(kk2, h0p[0], ak2[0]); ak2[1] = pkfma(kk2, h0p[1], ak2[1]);
                ak2[2] = pkfma(kk2, h1p[0], ak2[2]); ak2[3] = pkfma(kk2, h1p[1], ak2[3]);
                av2[0] = pkfma(vv2, h0p[0], av2[0]); av2[1] = pkfma(vv2, h0p[1], av2[1]);
                av2[2] = pkfma(vv2, h1p[0], av2[2]); av2[3] = pkfma(vv2, h1p[1], av2[3]);
            }
        }
        float kk[8], kx[8], kn[8];
        #pragma unroll
        for (int s = 0; s < 8; ++s) {
            const int p = s >> 1, e = s & 1;
            qe2[p][e] = siluf(aq2[p][e]) * LOG2E;
            kk[s] = siluf(ak2[p][e]);
            S.sK[g][tl][s] = kk[s];
            S.sV[g][tl][s] = siluf(av2[p][e]);
            kx[s] = kk[s]; kn[s] = kk[s];
        }
        #pragma unroll
        for (int off = 32; off; off >>= 1) {
            #pragma unroll
            for (int s = 0; s < 8; ++s) {
                kx[s] = fmaxf(kx[s], __shfl_xor(kx[s], off));
                kn[s] = fminf(kn[s], __shfl_xor(kn[s], off));
            }
        }
        if ((tid & 63) == 0) {
            #pragma unroll
            for (int s = 0; s < 8; ++s) { S.skr[g][wg][0][s] = kx[s]; S.skr[g][wg][1][s] = kn[s]; }
        }
    }
    __syncthreads();

    // ---- C: attention row tl, single pass, global-bound shift; unroll 4 ----
    {
        float bnd2 = 0.f;
        #pragma unroll
        for (int s = 0; s < 8; ++s) {
            const float kx = fmaxf(S.skr[g][0][0][s], S.skr[g][1][0][s]);
            const float kn = fminf(S.skr[g][0][1][s], S.skr[g][1][1][s]);
            const float q = qe2[s >> 1][s & 1];
            bnd2 += fmaxf(q * kx, q * kn);
        }
        float l = 0.f;
        f32x2 t2[4];
        #pragma unroll
        for (int p = 0; p < 4; ++p) t2[p] = (f32x2){0.f, 0.f};
        #pragma unroll 4
        for (int j = 0; j < NDIM; ++j) {
            const float4 k0 = *(const float4*)&S.sK[g][j][0];
            const float4 k1 = *(const float4*)&S.sK[g][j][4];
            const f32x2* k0p = (const f32x2*)&k0;
            const f32x2* k1p = (const f32x2*)&k1;
            f32x2 d2 = {-bnd2, 0.f};
            d2 = pkfma(qe2[0], k0p[0], d2);
            d2 = pkfma(qe2[1], k0p[1], d2);
            d2 = pkfma(qe2[2], k1p[0], d2);
            d2 = pkfma(qe2[3], k1p[1], d2);
            const float e = fexp2(d2.x + d2.y);
            const float4 v0 = *(const float4*)&S.sV[g][j][0];
            const float4 v1 = *(const float4*)&S.sV[g][j][4];
            const f32x2* v0p = (const f32x2*)&v0;
            const f32x2* v1p = (const f32x2*)&v1;
            const f32x2 e2 = {e, e};
            l += e;
            t2[0] = pkfma(e2, v0p[0], t2[0]);
            t2[1] = pkfma(e2, v0p[1], t2[1]);
            t2[2] = pkfma(e2, v1p[0], t2[2]);
            t2[3] = pkfma(e2, v1p[1], t2[3]);
        }
        const float rl = frcp(l);
        #pragma unroll
        for (int s = 0; s < 8; ++s)
            S.sz[g][s][tl] = siluf(t2[s >> 1][s & 1] * rl);
    }
    __syncthreads();

    // ---- D: w[s,o] = silu(z @ Wout + bout). R on tids 0-127, J on 128-191 ----
    if (tid < 192) {
        const int gm = (tid < 128) ? 1 : 0;
        const int t2 = (tid < 128) ? tid : tid - 128;
        const int lo2 = gm ? 4 : 3;
        const int outd = 1 << lo2;
        const int s = t2 >> lo2, o = t2 & (outd - 1);
        const float* Wo = gm ? RWout : JWout;
        const float* bo = gm ? Rbout : Jbout;
        float a = bo[o];
        #pragma unroll 8
        for (int c = 0; c < NDIM / 4; ++c) {
            const float4 z4 = *(const float4*)&S.sz[gm][s][4 * c];
            a = fmaf(z4.x, Wo[(4 * c + 0) * outd + o], a);
            a = fmaf(z4.y, Wo[(4 * c + 1) * outd + o], a);
            a = fmaf(z4.z, Wo[(4 * c + 2) * outd + o], a);
            a = fmaf(z4.w, Wo[(4 * c + 3) * outd + o], a);
        }
        S.sw[gm][t2] = siluf(a);
    }
    __syncthreads();

    // ---- J scalar + R group sums ----
    if (tid < 64) {
        float v = S.sw[0][tid];
        #pragma unroll
        for (int off = 32; off; off >>= 1) v += __shfl_xor(v, off);
        if (tid == 0) *sJvp = v;
    } else if (tid < 96) {
        const int t = tid - 64, pq = t >> 3, c = t & 7;
        const int base = c * 16 + pq * 4;
        sg[t] = (double)S.sw[1][base] + (double)S.sw[1][base + 1]
              + (double)S.sw[1][base + 2] + (double)S.sw[1][base + 3];
    }
    __syncthreads();

    // ---- assembly: Rupper, Laplacian Rm, u = (J_eff - Rm Rm^T) dH ----
    const int ii = (tid >> 4) & 15, jj = tid & 15;
    {
        const double rij = sg[((ii >> 3) * 2 + (jj >> 3)) * 8 + (jj & 7)];
        const double rji = sg[((jj >> 3) * 2 + (ii >> 3)) * 8 + (ii & 7)];
        sRm[ii][jj] = rij * rij + rji * rji;
    }
    __syncthreads();

    if (tid < 16) {
        double a = 0.0;
        for (int j = 0; j < 16; ++j) a += sRm[tid][j];
        srs[tid] = a;
    }
    __syncthreads();

    {
        const double v = (ii == jj) ? srs[ii] : -sRm[ii][jj];
        __syncthreads();
        sRm[ii][jj] = v;
    }
    __syncthreads();

    if (tid < 16) {
        double a = 0.0;
        for (int j = 0; j < 16; ++j) a += sRm[tid][j] * sdH[j];
        svv[tid] = a;
    }
    __syncthreads();

    if (tid < 16) {
        double a = 0.0;
        for (int k = 0; k < 16; ++k) a += sRm[tid][k] * svv[k];
        const double sj = (double)(*sJvp);
        const double jterm = (tid < 8) ? 2.0 * sj * sdH[8 + tid]
                                       : -2.0 * sj * sdH[tid - 8];
        out[b * 16 + tid] = (float)(jterm - a);
    }
}

// ---------------------------------------------------------------------------
// One kernel, one block per batch: H phase -> LDS handoff -> JR phase.
// ---------------------------------------------------------------------------
__global__ __launch_bounds__(256) void k_all(
    const float* __restrict__ x,
    const float* __restrict__ HWin, const float* __restrict__ Hbin,
    const float* __restrict__ HAq, const float* __restrict__ HAk, const float* __restrict__ HAv,
    const float* __restrict__ HBq, const float* __restrict__ HBk, const float* __restrict__ HBv,
    const float* __restrict__ HWout, const float* __restrict__ Hbout,
    const float* __restrict__ JWin, const float* __restrict__ Jbin,
    const float* __restrict__ JAq, const float* __restrict__ JAk, const float* __restrict__ JAv,
    const float* __restrict__ JBq, const float* __restrict__ JBk, const float* __restrict__ JBv,
    const float* __restrict__ JWout, const float* __restrict__ Jbout,
    const float* __restrict__ RWin, const float* __restrict__ Rbin,
    const float* __restrict__ RAq, const float* __restrict__ RAk, const float* __restrict__ RAv,
    const float* __restrict__ RBq, const float* __restrict__ RBk, const float* __restrict__ RBv,
    const float* __restrict__ RWout, const float* __restrict__ Rbout,
    float* __restrict__ out)
{
    __shared__ SU S;
    __shared__ float  sdHf[16];
    __shared__ float  sJv;
    __shared__ double sdH[16], sg[32], sRm[16][17], srs[16], svv[16];

    const int b = blockIdx.x;

    h_path(b, threadIdx.x, S.h, x, HWin, Hbin, HAq, HAk, HAv,
           HBq, HBk, HBv, HWout, Hbout, sdHf);
    __syncthreads();   // inter-phase: sdHf visible; HS buffers dead

    jr_path(b, threadIdx.x, S.jr,
            JWin, Jbin, JAq, JAk, JAv, JBq, JBk, JBv, JWout, Jbout,
            RWin, Rbin, RAq, RAk, RAv, RBq, RBk, RBv, RWout, Rbout,
            sdHf, sdH, sg, sRm, srs, svv, &sJv, out);
}

// ---------------------------------------------------------------------------
extern "C" void kernel_launch(void* const* d_in, const int* in_sizes, int n_in,
                              void* d_out, int out_size, void* d_ws, size_t ws_size,
                              hipStream_t stream)
{
    const float* x = (const float*)d_in[0];
    float* out = (float*)d_out;

#define ARGS10(base) \
    (const float*)d_in[(base) + 0], (const float*)d_in[(base) + 1], \
    (const float*)d_in[(base) + 2], (const float*)d_in[(base) + 3], \
    (const float*)d_in[(base) + 4], (const float*)d_in[(base) + 5], \
    (const float*)d_in[(base) + 6], (const float*)d_in[(base) + 7], \
    (const float*)d_in[(base) + 8], (const float*)d_in[(base) + 9]

    k_all<<<dim3(512), dim3(256), 0, stream>>>(
        x, ARGS10(1), ARGS10(11), ARGS10(21), out);
#undef ARGS10
}